// Round 4
// baseline (718.598 us; speedup 1.0000x reference)
//
#include <hip/hip_runtime.h>
#include <math.h>

#define ORISIZE 256
#define KER 32
#define P 225            // ORISIZE - KER + 1
#define PP (P * P)       // 50625
#define HALF 16          // KER/2
#define FEPS 1e-5f
#define NSPLIT 32        // argmax parallel splits per (b,c)
#define CHUNK ((PP + NSPLIT - 1) / NSPLIT)  // 1583
#define TILE_W 32        // pooled columns per pool block
#define NTILE 8          // ceil(P / TILE_W)
#define RCH 8            // image rows per streamed chunk
#define RING 40          // ring rows: live window is 39 (32 old + 7 new)

// ---------------------------------------------------------------------------
// Fused stage 1+2: softmax(axis=1) + entropy + 32x32 avgpool -> filter fields.
// One block per (tile, b): 32 pooled columns, all 225 pooled rows, image rows
// streamed in chunks of 8 through an LDS ring of horizontal sums.
// Summation order is IDENTICAL to the verified 2-kernel version (dx 0..31
// fresh adds per row, then dy 0..31 fresh adds over rows) -> bit-exact.
//   F[0][b][i] = sv - 0.1*ev,  F[1][b][i] = (1-sv) - 0.1*ev
// ---------------------------------------------------------------------------
__global__ __launch_bounds__(256) void pool_kernel(
    const float* __restrict__ infeat, float* __restrict__ F, int B) {
  int tile = blockIdx.x;
  int b = blockIdx.y;
  int tid = threadIdx.x;
  int px0 = tile * TILE_W;
  int tw = P - px0;
  if (tw > TILE_W) tw = TILE_W;      // tile 7 -> 1
  int iw = tw + KER - 1;             // input cols needed, <= 63

  __shared__ float s_p[RCH][64];     // current chunk p0 rows
  __shared__ float s_e[RCH][64];     // current chunk entropy rows
  __shared__ float ring_p[RING][TILE_W];  // horizontal sums, last RING rows
  __shared__ float ring_e[RING][TILE_W];

  const float* in0 = infeat + (size_t)(b * 2 + 0) * ORISIZE * ORISIZE + px0;
  const float* in1 = infeat + (size_t)(b * 2 + 1) * ORISIZE * ORISIZE + px0;

  for (int c0 = 0; c0 < ORISIZE; c0 += RCH) {
    // ---- load + softmax/entropy for rows c0..c0+7 ----
    for (int it = tid; it < RCH * 64; it += 256) {
      int r = it >> 6;
      int xi = it & 63;
      if (xi < iw) {
        int y = c0 + r;
        float a0 = in0[(size_t)y * ORISIZE + xi];
        float a1 = in1[(size_t)y * ORISIZE + xi];
        float m = fmaxf(a0, a1);
        float e0 = expf(a0 - m);
        float e1 = expf(a1 - m);
        float s = e0 + e1;
        float p0 = e0 / s;
        float p1 = e1 / s;
        float ent = -(p0 * logf(p0 + FEPS)) - (p1 * logf(p1 + FEPS));
        s_p[r][xi] = p0;
        s_e[r][xi] = ent;
      }
    }
    __syncthreads();  // s_p/s_e ready; also fences last chunk's vert reads
                      // of ring before this chunk's hsum overwrites slots

    // ---- horizontal 32-sum -> ring ----
    {
      int r = tid >> 5;
      int px = tid & 31;
      if (px < tw) {
        float accp = 0.f, acce = 0.f;
#pragma unroll
        for (int dx = 0; dx < KER; ++dx) {
          accp += s_p[r][px + dx];
          acce += s_e[r][px + dx];
        }
        int slot = (c0 + r) % RING;
        ring_p[slot][px] = accp;
        ring_e[slot][px] = acce;
      }
    }
    __syncthreads();  // ring rows c0..c0+7 ready

    // ---- vertical 32-sum for pooled rows py = c0-31 .. c0-24 ----
    {
      int pyi = tid >> 5;
      int px = tid & 31;
      int py = c0 - (KER - 1) + pyi;
      if (py >= 0 && py < P && px < tw) {
        float a = 0.f, e = 0.f;
        int slot = py % RING;
#pragma unroll
        for (int dy = 0; dy < KER; ++dy) {
          a += ring_p[slot][px];
          e += ring_e[slot][px];
          if (++slot == RING) slot = 0;
        }
        float sv = a * (1.f / (KER * KER));
        float ev = e * (1.f / (KER * KER));
        size_t o = (size_t)b * PP + (size_t)py * P + px0 + px;
        F[o] = sv - 0.1f * ev;
        F[(size_t)B * PP + o] = (1.0f - sv) - 0.1f * ev;
      }
    }
    // no barrier needed: next iteration's post-load barrier orders
    // this vert's ring reads before the next hsum's ring writes
  }
}

// ---------------------------------------------------------------------------
// Stage 3a: one suppression round, parallel. grid = (NSPLIT, B, 2).
// Reconstructs prior boxes from partials, scans its chunk with mask-multiply
// semantics (masked -> exactly 0.0), reference tie-break (max, then min idx).
// ---------------------------------------------------------------------------
__global__ __launch_bounds__(256) void argmax_round_kernel(
    const float* __restrict__ F, float* __restrict__ pval,
    int* __restrict__ pidx, int B, int kk) {
  int s = blockIdx.x;
  int b = blockIdx.y;
  int c = blockIdx.z;
  int tid = threadIdx.x;

  __shared__ int bys[16], bxs[16];
  __shared__ float rv[256];
  __shared__ int ri[256];

  if (tid < kk) {  // kk <= 16: one thread per prior round
    int j = tid;
    int pbase = ((j * B + b) * 2 + c) * NSPLIT;
    float bv = -INFINITY;
    int bi = PP;
    for (int ss = 0; ss < NSPLIT; ++ss) {
      float v = pval[pbase + ss];
      int ii = pidx[pbase + ss];
      if (v > bv || (v == bv && ii < bi)) { bv = v; bi = ii; }
    }
    int py = bi / P;
    bys[j] = py;
    bxs[j] = bi - py * P;
  }
  __syncthreads();

  const float* f = F + ((size_t)c * B + b) * PP;
  int base = s * CHUNK;
  int end = base + CHUNK;
  if (end > PP) end = PP;

  float best = -INFINITY;
  int bi = PP;
  for (int i = base + tid; i < end; i += 256) {
    float v = f[i];
    int py = i / P;
    int px = i - py * P;
    bool masked = false;
    for (int j = 0; j < kk; ++j) {
      if (py >= bys[j] - HALF && py < bys[j] + HALF && px >= bxs[j] - HALF &&
          px < bxs[j] + HALF)
        masked = true;
    }
    if (masked) v = 0.0f;  // mask-multiply, NOT -inf
    if (v > best) {        // strict > keeps earliest index per thread
      best = v;
      bi = i;
    }
  }
  rv[tid] = best;
  ri[tid] = bi;
  __syncthreads();
  for (int sh = 128; sh > 0; sh >>= 1) {
    if (tid < sh) {
      float v2 = rv[tid + sh];
      int i2 = ri[tid + sh];
      if (v2 > rv[tid] || (v2 == rv[tid] && i2 < ri[tid])) {
        rv[tid] = v2;
        ri[tid] = i2;
      }
    }
    __syncthreads();
  }
  if (tid == 0) {
    int p = ((kk * B + b) * 2 + c) * NSPLIT + s;
    pval[p] = rv[0];
    pidx[p] = ri[0];
  }
}

// ---------------------------------------------------------------------------
// Stage 3b: final reduce of all rounds' partials -> provalue, pointXY, selyx.
// ---------------------------------------------------------------------------
__global__ __launch_bounds__(256) void finish_kernel(
    const float* __restrict__ pval, const int* __restrict__ pidx, int B, int K,
    float* __restrict__ out_val, float* __restrict__ out_xy,
    int* __restrict__ selyx) {
  int total = B * 2 * K;
  for (int t = blockIdx.x * blockDim.x + threadIdx.x; t < total;
       t += gridDim.x * blockDim.x) {
    int c = t & 1;
    int rem = t >> 1;
    int b = rem % B;
    int kk = rem / B;
    int pbase = ((kk * B + b) * 2 + c) * NSPLIT;
    float bv = -INFINITY;
    int bi = PP;
    for (int ss = 0; ss < NSPLIT; ++ss) {
      float v = pval[pbase + ss];
      int ii = pidx[pbase + ss];
      if (v > bv || (v == bv && ii < bi)) { bv = v; bi = ii; }
    }
    int py = bi / P;
    int px = bi - py * P;
    int slot = (c * K + kk) * B + b;
    out_val[slot] = bv;
    out_xy[slot * 4 + 0] = (float)px;
    out_xy[slot * 4 + 1] = (float)(px + KER - 1);
    out_xy[slot * 4 + 2] = (float)py;
    out_xy[slot * 4 + 3] = (float)(py + KER - 1);
    selyx[slot * 2 + 0] = py;
    selyx[slot * 2 + 1] = px;
  }
}

// ---------------------------------------------------------------------------
// Stage 4: fused gather. One block per (slot, tc) channel-plane; each thread
// copies 4 consecutive pixels (one 16B-aligned float4 store). tc decode:
// 0-1 -> infeat, 2..C+1 -> FeatureDA, C+2 -> labelTpesudo, C+3 -> labelT.
// ---------------------------------------------------------------------------
__global__ __launch_bounds__(256) void extract_kernel(
    const float* __restrict__ infeat, const float* __restrict__ FeatureDA,
    const float* __restrict__ lp, const float* __restrict__ lt,
    const int* __restrict__ selyx, int B, int C, float* __restrict__ out,
    size_t o_feat, size_t o_lp, size_t o_lt) {
  int TC = C + 4;
  int plane = blockIdx.x;
  int slot = plane / TC;
  int tc = plane - slot * TC;
  int b = slot % B;
  int py = selyx[slot * 2 + 0];
  int px = selyx[slot * 2 + 1];

  const float* src;
  int ch, srcC;
  size_t dsto;
  if (tc < 2) {
    src = infeat; ch = tc; srcC = 2;
    dsto = ((size_t)slot * 2 + ch) * 1024;
  } else if (tc < 2 + C) {
    src = FeatureDA; ch = tc - 2; srcC = C;
    dsto = o_feat + ((size_t)slot * C + ch) * 1024;
  } else if (tc == 2 + C) {
    src = lp; ch = 0; srcC = 1;
    dsto = o_lp + (size_t)slot * 1024;
  } else {
    src = lt; ch = 0; srcC = 1;
    dsto = o_lt + (size_t)slot * 1024;
  }

  int pix = threadIdx.x * 4;  // 4 | 32 -> all 4 pixels in the same image row
  int dy = pix >> 5;
  int dx = pix & 31;
  const float* srow =
      src + (((size_t)b * srcC + ch) * ORISIZE + (py + dy)) * ORISIZE + px + dx;
  float4 v;
  v.x = srow[0];
  v.y = srow[1];
  v.z = srow[2];
  v.w = srow[3];
  *reinterpret_cast<float4*>(out + dsto + pix) = v;  // dsto%1024==0 -> 16B ok
}

extern "C" void kernel_launch(void* const* d_in, const int* in_sizes, int n_in,
                              void* d_out, int out_size, void* d_ws,
                              size_t ws_size, hipStream_t stream) {
  const float* infeat = (const float*)d_in[0];
  const float* labelTpesudo = (const float*)d_in[1];
  const float* labelT = (const float*)d_in[2];
  const float* FeatureDA = (const float*)d_in[3];

  int B = in_sizes[0] / (2 * ORISIZE * ORISIZE);  // 32
  int C = in_sizes[3] / (B * ORISIZE * ORISIZE);  // 64
  long per_patch = (long)(C + 4) * KER * KER + 5;
  int K = (int)((long)out_size / (2L * B * per_patch));
  if (K < 1) K = 1;
  if (K > 16) K = 16;
  int npatch = 2 * K * B;

  // workspace layout
  float* F = (float*)d_ws;                          // [2][B][PP]
  float* pval = F + (size_t)2 * B * PP;             // [K][B][2][NSPLIT]
  int* pidx = (int*)(pval + (size_t)16 * B * 2 * NSPLIT);
  int* selyx = pidx + (size_t)16 * B * 2 * NSPLIT;  // [npatch][2]

  // output layout (floats), concatenated in reference return order
  float* out = (float*)d_out;
  size_t o_feat = (size_t)npatch * 2 * KER * KER;
  size_t o_lp = o_feat + (size_t)npatch * C * KER * KER;
  size_t o_lt = o_lp + (size_t)npatch * KER * KER;
  size_t o_val = o_lt + (size_t)npatch * KER * KER;
  size_t o_xy = o_val + (size_t)npatch;

  pool_kernel<<<dim3(NTILE, B), dim3(256), 0, stream>>>(infeat, F, B);

  for (int kk = 0; kk < K; ++kk) {
    argmax_round_kernel<<<dim3(NSPLIT, B, 2), dim3(256), 0, stream>>>(
        F, pval, pidx, B, kk);
  }
  finish_kernel<<<dim3(1), dim3(256), 0, stream>>>(pval, pidx, B, K,
                                                   out + o_val, out + o_xy,
                                                   selyx);

  int nplanes = npatch * (C + 4);
  extract_kernel<<<dim3(nplanes), dim3(256), 0, stream>>>(
      infeat, FeatureDA, labelTpesudo, labelT, selyx, B, C, out, o_feat, o_lp,
      o_lt);
}